// Round 8
// baseline (207.213 us; speedup 1.0000x reference)
//
#include <hip/hip_runtime.h>
#include <hip/hip_bf16.h>

#define EPSV 1e-5f
#define PITCH 34                 // shorts per pcol (32 ci + 2 pad) = 68 B = 17 dw, coprime w/32 banks
#define PCOLS 516
#define PARSZ (PCOLS * PITCH)    // shorts per parity plane

typedef short bf16x8 __attribute__((ext_vector_type(8)));
typedef short bf16x4 __attribute__((ext_vector_type(4)));
typedef float f32x4  __attribute__((ext_vector_type(4)));

__device__ __forceinline__ short f2bf(float f){
  unsigned u = __float_as_uint(f);
  u += 0x7fff + ((u >> 16) & 1);     // RNE
  return (short)(u >> 16);
}
__device__ __forceinline__ int pk2(float a, float b){
  __hip_bfloat162 h = __float22bfloat162_rn(float2{a, b});
  return *reinterpret_cast<int*>(&h);
}

// ---------------------------------------------------------------------------
// Kernel A: Wb[b][j][co][ci] = bf16(conv_w[co][ci][j] + scale*(B@A)[b][co][ci*5+j])
// ---------------------------------------------------------------------------
__global__ void build_weights(const float* __restrict__ A_flat,
                              const float* __restrict__ B_flat,
                              const float* __restrict__ conv_w,
                              const float* __restrict__ scale_p,
                              short* __restrict__ Wb){
  int idx = blockIdx.x * 256 + threadIdx.x;   // ((b*5+j)*128 + co)*64 + ci
  int ci = idx & 63;
  int co = (idx >> 6) & 127;
  int bj = idx >> 13;          // 0..159
  int b  = bj / 5;
  int j  = bj - 5 * b;
  int m  = ci * 5 + j;
  const float* Bp = B_flat + (b * 128 + co) * 8;
  const float* Ap = A_flat + b * 8 * 320 + m;
  float d = 0.f;
#pragma unroll
  for (int r = 0; r < 8; ++r) d = fmaf(Bp[r], Ap[r * 320], d);
  float w = conv_w[co * 320 + m] + scale_p[0] * d;
  Wb[idx] = f2bf(w);
}

// ---------------------------------------------------------------------------
// Kernel B: block = (sample, group), 512 thr / 8 waves, 1 blk/CU (reg-deep).
// 4 phases (ci-chunk x t-half). Staging: 16 float4 loads ALL in flight
// (pf[16], launch_bounds(512,2) gives the register budget), then pack to
// parity-split bf16 LDS (PITCH 17 dw: writes hit every bank exactly once).
// ---------------------------------------------------------------------------
__global__ __launch_bounds__(512, 2)
void conv_gn_mfma(const float* __restrict__ x,
                  const short* __restrict__ Wb,
                  const float* __restrict__ conv_b,
                  const float* __restrict__ gamma,
                  const float* __restrict__ beta,
                  float* __restrict__ out){
  __shared__ short xls[2 * PARSZ];     // 70176 B
  __shared__ float redS[8], redQ[8], bc2[2];

  const int bid    = blockIdx.x;
  const int sample = ((bid & 7) << 5) + (bid >> 5);  // R2 swizzle: same XCD per sample
  const int g      = (bid >> 3) & 3;
  const int b      = sample >> 3;
  const int tid    = threadIdx.x;
  const int lane   = tid & 63;
  const int wid    = tid >> 6;          // 0..7
  const int l16    = lane & 15;
  const int lk     = lane >> 4;         // 0..3

  f32x4 acc[2][8];
#pragma unroll
  for (int m2 = 0; m2 < 2; ++m2)
#pragma unroll
    for (int n = 0; n < 8; ++n) acc[m2][n] = (f32x4){0.f,0.f,0.f,0.f};

  const size_t wb_base = (size_t)b * 5 * 128 * 64;
  const float* xsamp = x + (size_t)sample * 64 * 2048;
  const int hw_ = tid >> 5, hci = tid & 31;      // halo role (tid<96)

#pragma unroll
  for (int ph = 0; ph < 4; ++ph) {
    const int ch = ph >> 1;             // ci chunk
    const int th = ph & 1;              // t-half
    if (ph) __syncthreads();            // prev compute done before overwrite

    // ---- stage: x[ch*32..+32][th*1024 .. +1024) -> parity-split bf16 LDS
    {
      const float* xr = xsamp + (size_t)(ch * 32 + wid * 4) * 2048 + th * 1024;
      float4 pf[16];
#pragma unroll
      for (int p = 0; p < 4; ++p)
#pragma unroll
        for (int r = 0; r < 4; ++r)
          pf[p*4 + r] = *(const float4*)(xr + (size_t)r * 2048 + p * 256 + lane * 4);

      float hv = 0.f;
      if (tid < 96) {
        int xc = th * 1024 + (hw_ == 0 ? -2 : hw_ == 1 ? -1 : 1024);
        if (xc >= 0 && xc < 2048) hv = xsamp[(size_t)(ch * 32 + hci) * 2048 + xc];
      }

#pragma unroll
      for (int p = 0; p < 4; ++p) {
        float4 v0 = pf[p*4+0], v1 = pf[p*4+1], v2 = pf[p*4+2], v3 = pf[p*4+3];
        const int pe = p * 128 + 2 * (int)lane + 1;   // even-parity pcol of col c
        // even cols c, c+2  (components .x, .z)
        *(int2*)&xls[ pe      * PITCH + wid * 4] = int2{pk2(v0.x, v1.x), pk2(v2.x, v3.x)};
        *(int2*)&xls[(pe + 1) * PITCH + wid * 4] = int2{pk2(v0.z, v1.z), pk2(v2.z, v3.z)};
        // odd cols c+1, c+3  (components .y, .w)
        *(int2*)&xls[PARSZ +  pe      * PITCH + wid * 4] = int2{pk2(v0.y, v1.y), pk2(v2.y, v3.y)};
        *(int2*)&xls[PARSZ + (pe + 1) * PITCH + wid * 4] = int2{pk2(v0.w, v1.w), pk2(v2.w, v3.w)};
      }
      if (tid < 96) {   // halos: pcol0 (xcol -2 even / -1 odd), pcol513 (xcol +1024 even)
        int prow = (hw_ == 2) ? 513 : 0;
        xls[(hw_ == 1 ? PARSZ : 0) + prow * PITCH + hci] = f2bf(hv);
      }
    }
    __syncthreads();

    // ---- compute: 5 taps x 4 n-frags x 2 m-frags, K=32 (this ci chunk)
#pragma unroll
    for (int j = 0; j < 5; ++j) {
      const short* apb = Wb + wb_base + (size_t)(j * 128 + g * 32) * 64 + ch * 32 + lk * 8;
      bf16x8 a0 = *(const bf16x8*)(apb + (size_t)l16 * 64);
      bf16x8 a1 = *(const bf16x8*)(apb + (size_t)(l16 + 16) * 64);
      const short* arr = xls + ((j & 1) ? PARSZ : 0);
      const int joff = j >> 1;          // 0,0,1,1,2
#pragma unroll
      for (int nn = 0; nn < 4; ++nn) {
        int pcol = wid * 64 + nn * 16 + l16 + joff;    // t within half + tap offset
        const short* bp = arr + pcol * PITCH + lk * 8;
        bf16x4 lo = *(const bf16x4*)bp;
        bf16x4 hi = *(const bf16x4*)(bp + 4);
        bf16x8 bfr = {lo[0],lo[1],lo[2],lo[3],hi[0],hi[1],hi[2],hi[3]};
        const int n = th * 4 + nn;                     // static (ph unrolled)
        acc[0][n] = __builtin_amdgcn_mfma_f32_16x16x32_bf16(a0, bfr, acc[0][n], 0, 0, 0);
        acc[1][n] = __builtin_amdgcn_mfma_f32_16x16x32_bf16(a1, bfr, acc[1][n], 0, 0, 0);
      }
    }
  }

  // ---- epilogue: bias + ReLU + GroupNorm over 32co x 1024t
  float cb_[2][4], ga_[2][4], be_[2][4];
#pragma unroll
  for (int m2 = 0; m2 < 2; ++m2)
#pragma unroll
    for (int r = 0; r < 4; ++r) {
      int co = g * 32 + m2 * 16 + lk * 4 + r;
      cb_[m2][r] = conv_b[co];
      ga_[m2][r] = gamma[co];
      be_[m2][r] = beta[co];
    }
  float s1 = 0.f, s2 = 0.f;
#pragma unroll
  for (int m2 = 0; m2 < 2; ++m2)
#pragma unroll
    for (int n = 0; n < 8; ++n)
#pragma unroll
      for (int r = 0; r < 4; ++r) {
        float v = acc[m2][n][r] + cb_[m2][r];
        v = v > 0.f ? v : 0.f;
        acc[m2][n][r] = v;
        s1 += v;
        s2 = fmaf(v, v, s2);
      }
#pragma unroll
  for (int off = 32; off; off >>= 1) {
    s1 += __shfl_down(s1, off);
    s2 += __shfl_down(s2, off);
  }
  if (lane == 0) { redS[wid] = s1; redQ[wid] = s2; }
  __syncthreads();
  if (tid == 0) {
    float a = 0.f, q = 0.f;
#pragma unroll
    for (int w = 0; w < 8; ++w) { a += redS[w]; q += redQ[w]; }
    float mean = a * (1.f / 32768.f);
    float var  = q * (1.f / 32768.f) - mean * mean;
    bc2[0] = mean;
    bc2[1] = rsqrtf(var + EPSV);
  }
  __syncthreads();
  const float mean = bc2[0], inv = bc2[1];
  float* ob = out + (size_t)sample * 128 * 1024;
#pragma unroll
  for (int m2 = 0; m2 < 2; ++m2)
#pragma unroll
    for (int r = 0; r < 4; ++r) {
      int co = g * 32 + m2 * 16 + lk * 4 + r;
      float aa = ga_[m2][r] * inv;
      float bb = be_[m2][r] - mean * aa;
      float* orow = ob + (size_t)co * 1024 + l16;
#pragma unroll
      for (int n = 0; n < 8; ++n) {
        int t = (n >> 2) * 512 + wid * 64 + (n & 3) * 16;
        orow[t] = acc[m2][n][r] * aa + bb;
      }
    }
}

// ---------------------------------------------------------------------------
extern "C" void kernel_launch(void* const* d_in, const int* in_sizes, int n_in,
                              void* d_out, int out_size, void* d_ws, size_t ws_size,
                              hipStream_t stream) {
  const float* x       = (const float*)d_in[0];
  const float* A_flat  = (const float*)d_in[1];
  const float* B_flat  = (const float*)d_in[2];
  const float* conv_w  = (const float*)d_in[3];
  const float* conv_b  = (const float*)d_in[4];
  const float* gamma   = (const float*)d_in[5];
  const float* beta    = (const float*)d_in[6];
  const float* scale_p = (const float*)d_in[9];

  float* out = (float*)d_out;
  short* Wb  = (short*)d_ws;   // 32*5*128*64 bf16 = 2.62 MB

  build_weights<<<5120, 256, 0, stream>>>(A_flat, B_flat, conv_w, scale_p, Wb);
  conv_gn_mfma<<<1024, 512, 0, stream>>>(x, Wb, conv_b, gamma, beta, out);
}

// Round 9
// 92.079 us; speedup vs baseline: 2.2504x; 2.2504x over previous
//
#include <hip/hip_runtime.h>
#include <hip/hip_bf16.h>

#define EPSV 1e-5f
#define PITCH 36      // shorts per LDS column (32 ci data + 4 pad) = 18 dw
#define NCOL 2052

typedef short bf16x8 __attribute__((ext_vector_type(8)));
typedef short bf16x4 __attribute__((ext_vector_type(4)));
typedef float f32x4  __attribute__((ext_vector_type(4)));

__device__ __forceinline__ short f2bf(float f){
  unsigned u = __float_as_uint(f);
  u += 0x7fff + ((u >> 16) & 1);     // RNE
  return (short)(u >> 16);
}
__device__ __forceinline__ int pk2(float a, float b){
  __hip_bfloat162 h = __float22bfloat162_rn(float2{a, b});
  return *reinterpret_cast<int*>(&h);
}

// slot-XOR swizzle: row = 18 dw, data = 8 slots x 2 dw (4 shorts).
// addr_sh(col, slot) = col*PITCH + 4*(slot ^ ((col>>4)&3))
__device__ __forceinline__ int swz(int col, int slot){
  return col * PITCH + 4 * (slot ^ ((col >> 4) & 3));
}

// ---------------------------------------------------------------------------
// Kernel A: Wb[b][j][co][ci] = bf16(conv_w[co][ci][j] + scale*(B@A)[b][co][ci*5+j])
// ---------------------------------------------------------------------------
__global__ void build_weights(const float* __restrict__ A_flat,
                              const float* __restrict__ B_flat,
                              const float* __restrict__ conv_w,
                              const float* __restrict__ scale_p,
                              short* __restrict__ Wb){
  int idx = blockIdx.x * 256 + threadIdx.x;   // ((b*5+j)*128 + co)*64 + ci
  int ci = idx & 63;
  int co = (idx >> 6) & 127;
  int bj = idx >> 13;          // 0..159
  int b  = bj / 5;
  int j  = bj - 5 * b;
  int m  = ci * 5 + j;
  const float* Bp = B_flat + (b * 128 + co) * 8;
  const float* Ap = A_flat + b * 8 * 320 + m;
  float d = 0.f;
#pragma unroll
  for (int r = 0; r < 8; ++r) d = fmaf(Bp[r], Ap[r * 320], d);
  float w = conv_w[co * 320 + m] + scale_p[0] * d;
  Wb[idx] = f2bf(w);
}

// ---------------------------------------------------------------------------
// Kernel B: R2 structure verbatim (block = sample x group, 512 thr, 2 phases,
// full-t LDS tile, 80-MFMA bursts) + slot-XOR swizzle on LDS writes/reads.
// ---------------------------------------------------------------------------
__global__ __launch_bounds__(512, 2)
void conv_gn_mfma(const float* __restrict__ x,
                  const short* __restrict__ Wb,
                  const float* __restrict__ conv_b,
                  const float* __restrict__ gamma,
                  const float* __restrict__ beta,
                  float* __restrict__ out){
  __shared__ short xl[NCOL * PITCH];          // 147744 B: [col][slot-swizzled ci]
  __shared__ float redS[8], redQ[8], bc2[2];

  const int bid    = blockIdx.x;
  const int sample = ((bid & 7) << 5) + (bid >> 5);  // 4 group-blocks 8 bids apart
  const int g      = (bid >> 3) & 3;
  const int b      = sample >> 3;
  const int tid    = threadIdx.x;
  const int lane   = tid & 63;
  const int wid    = tid >> 6;       // 0..7
  const int l16    = lane & 15;
  const int lk     = lane >> 4;      // 0..3 (k-group)
  const int t0w    = wid << 7;       // wave owns t in [t0w, t0w+128)

  f32x4 acc[2][8];
#pragma unroll
  for (int m2 = 0; m2 < 2; ++m2)
#pragma unroll
    for (int n = 0; n < 8; ++n) acc[m2][n] = (f32x4){0.f, 0.f, 0.f, 0.f};

  const size_t wb_base = (size_t)b * 5 * 128 * 64;

  for (int ch = 0; ch < 2; ++ch) {
    if (ch) __syncthreads();         // compute(ch=0) done before overwrite
    // ---- stage chunk: x[sample][ch*32 .. +32][0..2048) -> xl, transposed+bf16
    {
      const float* xs = x + ((size_t)sample * 64 + ch * 32 + wid * 4) * 2048;
      if (tid < 72) {                // zero pad cols 0,1 (x=-2,-1) and 2050,2051
        int cc = tid / 18, dw = tid % 18;
        int col = (cc < 2) ? cc : (2048 + cc);
        *(int*)((char*)xl + col * 72 + dw * 4) = 0;   // full-row zero: swizzle-invariant
      }
#pragma unroll 2
      for (int pass = 0; pass < 8; ++pass) {
        int cb = pass * 256 + lane * 4;              // x col base (16B aligned)
        const float4 v0 = *(const float4*)(xs + 0 * 2048 + cb);
        const float4 v1 = *(const float4*)(xs + 1 * 2048 + cb);
        const float4 v2 = *(const float4*)(xs + 2 * 2048 + cb);
        const float4 v3 = *(const float4*)(xs + 3 * 2048 + cb);
        bf16x4 p0 = {f2bf(v0.x), f2bf(v1.x), f2bf(v2.x), f2bf(v3.x)};
        bf16x4 p1 = {f2bf(v0.y), f2bf(v1.y), f2bf(v2.y), f2bf(v3.y)};
        bf16x4 p2 = {f2bf(v0.z), f2bf(v1.z), f2bf(v2.z), f2bf(v3.z)};
        bf16x4 p3 = {f2bf(v0.w), f2bf(v1.w), f2bf(v2.w), f2bf(v3.w)};
        const int c0 = cb + 2;                       // LDS col of x col cb
        *(bf16x4*)&xl[swz(c0,     wid)] = p0;        // slot = wid (2dw each)
        *(bf16x4*)&xl[swz(c0 + 1, wid)] = p1;
        *(bf16x4*)&xl[swz(c0 + 2, wid)] = p2;
        *(bf16x4*)&xl[swz(c0 + 3, wid)] = p3;
      }
    }
    __syncthreads();
    // ---- compute: 5 taps x (K=32 over this chunk's ci) x 8 n-frags x 2 m-frags
#pragma unroll
    for (int j = 0; j < 5; ++j) {
      const short* apb = Wb + wb_base + ((size_t)j * 128 + g * 32) * 64 + ch * 32 + lk * 8;
      bf16x8 a0 = *(const bf16x8*)(apb + (size_t)(l16)      * 64);
      bf16x8 a1 = *(const bf16x8*)(apb + (size_t)(l16 + 16) * 64);
#pragma unroll
      for (int n = 0; n < 8; ++n) {
        int c = 2 * (t0w + n * 16 + l16) + j;        // LDS col (= x col + 2)
        bf16x4 lo = *(const bf16x4*)&xl[swz(c, 2 * lk)];
        bf16x4 hi = *(const bf16x4*)&xl[swz(c, 2 * lk + 1)];
        bf16x8 bfr = {lo[0], lo[1], lo[2], lo[3], hi[0], hi[1], hi[2], hi[3]};
        acc[0][n] = __builtin_amdgcn_mfma_f32_16x16x32_bf16(a0, bfr, acc[0][n], 0, 0, 0);
        acc[1][n] = __builtin_amdgcn_mfma_f32_16x16x32_bf16(a1, bfr, acc[1][n], 0, 0, 0);
      }
    }
  }

  // ---- epilogue: bias + ReLU + GroupNorm (stats over all 8 waves = 32co x 1024t)
  float cb_[2][4], ga_[2][4], be_[2][4];
#pragma unroll
  for (int m2 = 0; m2 < 2; ++m2)
#pragma unroll
    for (int r = 0; r < 4; ++r) {
      int co = g * 32 + m2 * 16 + lk * 4 + r;
      cb_[m2][r] = conv_b[co];
      ga_[m2][r] = gamma[co];
      be_[m2][r] = beta[co];
    }
  float s1 = 0.f, s2 = 0.f;
#pragma unroll
  for (int m2 = 0; m2 < 2; ++m2)
#pragma unroll
    for (int n = 0; n < 8; ++n)
#pragma unroll
      for (int r = 0; r < 4; ++r) {
        float v = acc[m2][n][r] + cb_[m2][r];
        v = v > 0.f ? v : 0.f;
        acc[m2][n][r] = v;
        s1 += v;
        s2 = fmaf(v, v, s2);
      }
#pragma unroll
  for (int off = 32; off; off >>= 1) {
    s1 += __shfl_down(s1, off);
    s2 += __shfl_down(s2, off);
  }
  if (lane == 0) { redS[wid] = s1; redQ[wid] = s2; }
  __syncthreads();
  if (tid == 0) {
    float a = 0.f, q = 0.f;
#pragma unroll
    for (int w = 0; w < 8; ++w) { a += redS[w]; q += redQ[w]; }
    float mean = a * (1.f / 32768.f);
    float var  = q * (1.f / 32768.f) - mean * mean;
    bc2[0] = mean;
    bc2[1] = rsqrtf(var + EPSV);
  }
  __syncthreads();
  const float mean = bc2[0], inv = bc2[1];
  float* ob = out + (size_t)sample * 128 * 1024;
#pragma unroll
  for (int m2 = 0; m2 < 2; ++m2)
#pragma unroll
    for (int r = 0; r < 4; ++r) {
      int co = g * 32 + m2 * 16 + lk * 4 + r;
      float aa = ga_[m2][r] * inv;
      float bb = be_[m2][r] - mean * aa;
      float* orow = ob + (size_t)co * 1024 + t0w + l16;
#pragma unroll
      for (int n = 0; n < 8; ++n)
        orow[n * 16] = acc[m2][n][r] * aa + bb;
    }
}

// ---------------------------------------------------------------------------
extern "C" void kernel_launch(void* const* d_in, const int* in_sizes, int n_in,
                              void* d_out, int out_size, void* d_ws, size_t ws_size,
                              hipStream_t stream) {
  const float* x       = (const float*)d_in[0];
  const float* A_flat  = (const float*)d_in[1];
  const float* B_flat  = (const float*)d_in[2];
  const float* conv_w  = (const float*)d_in[3];
  const float* conv_b  = (const float*)d_in[4];
  const float* gamma   = (const float*)d_in[5];
  const float* beta    = (const float*)d_in[6];
  const float* scale_p = (const float*)d_in[9];

  float* out = (float*)d_out;
  short* Wb  = (short*)d_ws;   // 32*5*128*64 bf16 = 2.62 MB

  build_weights<<<5120, 256, 0, stream>>>(A_flat, B_flat, conv_w, scale_p, Wb);
  conv_gn_mfma<<<1024, 512, 0, stream>>>(x, Wb, conv_b, gamma, beta, out);
}